// Round 8
// baseline (352.736 us; speedup 1.0000x reference)
//
#include <hip/hip_runtime.h>
#include <hip/hip_fp16.h>

// SkipGram negative-sampling loss. B=32768, K=16, D=128, fp32 inputs.
// Round 8: R7 structure (hw-fp8 e4m3 con table, 128-B row gathers = 21
// cache lines/element, measured floor main ~= 0.5us*lines + 7us), plus:
// fold the final reduction into skipgram_main via the last-block-done
// pattern (native int atomicAdd on a counter -- fire-and-forget hw add,
// NOT the R5 fp32 CAS retry loop). Saves the 3rd launch (~3-4 us).
// Convert kernel zeroes the counter (stream-ordered before main).

constexpr int Bn = 32768;
constexpr int Kn = 16;
constexpr int WPB = 4;                    // waves per block (256 threads)
constexpr int NBLK = Bn / WPB;            // 8192 blocks
constexpr int VOCAB = 100000;
constexpr int DIM = 128;
constexpr size_t CNT_OFF  = 32768;        // byte offset of done-counter
constexpr size_t CONV_OFF = 65536;        // byte offset of fp8 table in d_ws
constexpr float SCALE = 256.0f;           // fp32 -> e4m3 pre-scale
constexpr float INV_SCALE = 1.0f / 256.0f;

typedef float f32x2 __attribute__((ext_vector_type(2)));

__device__ __forceinline__ float log_sigmoid_fast(float x) {
  // min(x,0) - log(1 + exp(-|x|)); log arg in (1,2] -> hw v_log_f32 accurate
  return fminf(x, 0.0f) - __logf(1.0f + __expf(-fabsf(x)));
}

// Multi-value butterfly step: C live values per lane -> C/2, partner mask M.
template<int M, int C>
__device__ __forceinline__ void tree_step(float* v, int lane) {
  const bool hi = (lane & M) != 0;
  const int H = C / 2;
#pragma unroll
  for (int j = 0; j < H; ++j) {
    float send = hi ? v[j] : v[j + H];
    float keep = hi ? v[j + H] : v[j];
    v[j] = keep + __shfl_xor(send, M, 64);
  }
}

// Decode two e4m3 bytes (packed in a ushort) -> float2, via hw converter.
__device__ __forceinline__ f32x2 dec2_fp8(unsigned short t) {
  return __builtin_amdgcn_cvt_pk_f32_fp8((int)(unsigned int)t, false);
}

// fp32 -> e4m3 table conversion via hw converter, 4 values/thread, streaming.
// Thread 0 also zeroes the done-counter used by skipgram_main's fused reduce.
__global__ __launch_bounds__(256) void convert_con(
    const float4* __restrict__ in, unsigned int* __restrict__ out, int n4,
    int* __restrict__ counter)
{
  int i = blockIdx.x * 256 + threadIdx.x;
  if (i == 0) *counter = 0;
  if (i >= n4) return;
  float4 v = in[i];
  int w = 0;
  w = __builtin_amdgcn_cvt_pk_fp8_f32(v.x * SCALE, v.y * SCALE, w, false);
  w = __builtin_amdgcn_cvt_pk_fp8_f32(v.z * SCALE, v.w * SCALE, w, true);
  out[i] = (unsigned int)w;
}

__global__ __launch_bounds__(256) void skipgram_main(
    const int* __restrict__ centrals,
    const int* __restrict__ pos_ctx,
    const int* __restrict__ neg_ctx,
    const float* __restrict__ word_emb,
    const unsigned short* __restrict__ con8,   // e4m3 table, 64 ushort/row
    float* __restrict__ block_sums,
    int* __restrict__ counter,
    float* __restrict__ loss_out)
{
  const int lane = threadIdx.x & 63;
  int b = blockIdx.x * WPB + (threadIdx.x >> 6);
  b = __builtin_amdgcn_readfirstlane(b);    // wave-uniform -> s_load path

  const float2* __restrict__ W = reinterpret_cast<const float2*>(word_emb);

  const int cw = centrals[b];
  const int pc = pos_ctx[b];
  int ni[Kn];
#pragma unroll
  for (int k = 0; k < Kn; ++k) ni[k] = neg_ctx[b * Kn + k];

  // Issue all 18 row gathers back-to-back.
  // word row: 512 B fp32 (float2/lane). con rows: 128 B fp8 (ushort/lane).
  const float2 wv = W[(size_t)cw * 64 + lane];
  const unsigned short cvb = con8[(size_t)pc * 64 + lane];
  unsigned short nvb[Kn];
#pragma unroll
  for (int k = 0; k < Kn; ++k) nvb[k] = con8[(size_t)ni[k] * 64 + lane];

  float v[Kn];
#pragma unroll
  for (int k = 0; k < Kn; ++k) {
    const f32x2 nf = dec2_fp8(nvb[k]);     // 1 hw cvt per row
    v[k] = fmaf(wv.x, nf.x, wv.y * nf.y);
  }

  // 16 partial dots -> one score per lane (15 shuffles), then close the
  // sum across the four 16-lane subgroups (2 shuffles).
  tree_step<1, 16>(v, lane);
  tree_step<2,  8>(v, lane);
  tree_step<4,  4>(v, lane);
  tree_step<8,  2>(v, lane);
  float s = v[0];
  s += __shfl_xor(s, 16, 64);
  s += __shfl_xor(s, 32, 64);
  s *= INV_SCALE;                          // undo e4m3 pre-scale

  float nls = log_sigmoid_fast(-s);        // one SIMD eval = all 16 scores
  nls += __shfl_xor(nls, 1, 64);
  nls += __shfl_xor(nls, 2, 64);
  nls += __shfl_xor(nls, 4, 64);
  nls += __shfl_xor(nls, 8, 64);           // neg_loss total (all lanes)

  const f32x2 cf = dec2_fp8(cvb);
  float pp = fmaf(wv.x, cf.x, wv.y * cf.y);
  pp += __shfl_xor(pp,  1, 64);
  pp += __shfl_xor(pp,  2, 64);
  pp += __shfl_xor(pp,  4, 64);
  pp += __shfl_xor(pp,  8, 64);
  pp += __shfl_xor(pp, 16, 64);
  pp += __shfl_xor(pp, 32, 64);
  pp *= INV_SCALE;                         // undo e4m3 pre-scale

  const float acc = log_sigmoid_fast(pp) + nls;

  __shared__ float smem[WPB];
  __shared__ int is_last;
  if (lane == 0) smem[threadIdx.x >> 6] = acc;
  __syncthreads();
  if (threadIdx.x == 0) {
    block_sums[blockIdx.x] = (smem[0] + smem[1]) + (smem[2] + smem[3]);
    __threadfence();                       // partial visible device-wide
    int old = atomicAdd(counter, 1);       // native int atomic (no CAS loop)
    is_last = (old == NBLK - 1) ? 1 : 0;
  }
  __syncthreads();

  if (is_last) {                           // one block does the final reduce
    __threadfence();                       // acquire all partials
    float t = 0.0f;
#pragma unroll
    for (int i = 0; i < NBLK / 256; ++i)
      t += block_sums[i * 256 + threadIdx.x];
    t += __shfl_xor(t,  1, 64);
    t += __shfl_xor(t,  2, 64);
    t += __shfl_xor(t,  4, 64);
    t += __shfl_xor(t,  8, 64);
    t += __shfl_xor(t, 16, 64);
    t += __shfl_xor(t, 32, 64);
    __shared__ float rsm[WPB];
    if (lane == 0) rsm[threadIdx.x >> 6] = t;
    __syncthreads();
    if (threadIdx.x == 0) {
      float tt = (rsm[0] + rsm[1]) + (rsm[2] + rsm[3]);
      loss_out[0] = -tt * (1.0f / (float)Bn);  // loss = -mean(pos+neg)
    }
  }
}

extern "C" void kernel_launch(void* const* d_in, const int* in_sizes, int n_in,
                              void* d_out, int out_size, void* d_ws, size_t ws_size,
                              hipStream_t stream) {
  const int*   centrals = (const int*)d_in[0];
  const int*   pos_ctx  = (const int*)d_in[1];
  const int*   neg_ctx  = (const int*)d_in[2];
  const float* word_emb = (const float*)d_in[3];
  const float* con_emb  = (const float*)d_in[4];
  float*       out      = (float*)d_out;

  float*        block_sums = (float*)d_ws;                         // 32 KB
  int*          counter    = (int*)((char*)d_ws + CNT_OFF);
  unsigned int* con_fp8    = (unsigned int*)((char*)d_ws + CONV_OFF); // 12.8 MB

  // 1) fp32 -> e4m3 conversion (streaming, 64 MB, hw cvt) + zero counter.
  const int n4 = VOCAB * DIM / 4;                                  // 3.2M float4
  convert_con<<<(n4 + 255) / 256, 256, 0, stream>>>(
      (const float4*)con_emb, con_fp8, n4, counter);

  // 2) gathers + dots + log-sigmoid + fused last-block final reduction.
  skipgram_main<<<NBLK, 256, 0, stream>>>(centrals, pos_ctx, neg_ctx,
                                          word_emb,
                                          (const unsigned short*)con_fp8,
                                          block_sums, counter, out);
}

// Round 9
// 137.574 us; speedup vs baseline: 2.5640x; 2.5640x over previous
//
#include <hip/hip_runtime.h>
#include <hip/hip_fp16.h>

// SkipGram negative-sampling loss. B=32768, K=16, D=128, fp32 inputs.
// Round 9: REVERT to the proven R7 structure. R8's last-block-done fused
// reduction regressed main 17 -> 238 us: __threadfence() (device-scope
// release) emits L2 writeback/invalidate ops on gfx950; x8192 blocks they
// serialize the TCC (VALUBusy 4.8%, HBM 170 GB/s, all pipes stalled).
// Cross-workgroup coherence on 8 non-coherent XCD L2s costs >> one launch.
//
// Final structure:
//  1) convert_con: fp32 -> e4m3 via hw v_cvt_pk_fp8_f32 (64 MB streaming,
//     ~10 us, HBM floor).
//  2) skipgram_main: per batch element, 18 row gathers (word row 512 B fp32,
//     17 con rows 128 B fp8 = 21 cache lines/elem), multi-value butterfly
//     reduction (15 shuffles for all 16 neg dots), one SIMD fast
//     log_sigmoid for all 16 scores. ~17 us = measured random-line floor.
//  3) skipgram_reduce: 8192 partials -> -mean (~3 us).

constexpr int Bn = 32768;
constexpr int Kn = 16;
constexpr int WPB = 4;                    // waves per block (256 threads)
constexpr int NBLK = Bn / WPB;            // 8192 blocks
constexpr int VOCAB = 100000;
constexpr int DIM = 128;
constexpr size_t CONV_OFF = 65536;        // byte offset of fp8 table in d_ws
constexpr float SCALE = 256.0f;           // fp32 -> e4m3 pre-scale
constexpr float INV_SCALE = 1.0f / 256.0f;

typedef float f32x2 __attribute__((ext_vector_type(2)));

__device__ __forceinline__ float log_sigmoid_fast(float x) {
  // min(x,0) - log(1 + exp(-|x|)); log arg in (1,2] -> hw v_log_f32 accurate
  return fminf(x, 0.0f) - __logf(1.0f + __expf(-fabsf(x)));
}

// Multi-value butterfly step: C live values per lane -> C/2, partner mask M.
template<int M, int C>
__device__ __forceinline__ void tree_step(float* v, int lane) {
  const bool hi = (lane & M) != 0;
  const int H = C / 2;
#pragma unroll
  for (int j = 0; j < H; ++j) {
    float send = hi ? v[j] : v[j + H];
    float keep = hi ? v[j + H] : v[j];
    v[j] = keep + __shfl_xor(send, M, 64);
  }
}

// Decode two e4m3 bytes (packed in a ushort) -> float2, via hw converter.
__device__ __forceinline__ f32x2 dec2_fp8(unsigned short t) {
  return __builtin_amdgcn_cvt_pk_f32_fp8((int)(unsigned int)t, false);
}

// fp32 -> e4m3 table conversion via hw converter, 4 values/thread, streaming.
__global__ __launch_bounds__(256) void convert_con(
    const float4* __restrict__ in, unsigned int* __restrict__ out, int n4)
{
  int i = blockIdx.x * 256 + threadIdx.x;
  if (i >= n4) return;
  float4 v = in[i];
  int w = 0;
  w = __builtin_amdgcn_cvt_pk_fp8_f32(v.x * SCALE, v.y * SCALE, w, false);
  w = __builtin_amdgcn_cvt_pk_fp8_f32(v.z * SCALE, v.w * SCALE, w, true);
  out[i] = (unsigned int)w;
}

__global__ __launch_bounds__(256) void skipgram_main(
    const int* __restrict__ centrals,
    const int* __restrict__ pos_ctx,
    const int* __restrict__ neg_ctx,
    const float* __restrict__ word_emb,
    const unsigned short* __restrict__ con8,   // e4m3 table, 64 ushort/row
    float* __restrict__ block_sums)
{
  const int lane = threadIdx.x & 63;
  int b = blockIdx.x * WPB + (threadIdx.x >> 6);
  b = __builtin_amdgcn_readfirstlane(b);    // wave-uniform -> s_load path

  const float2* __restrict__ W = reinterpret_cast<const float2*>(word_emb);

  const int cw = centrals[b];
  const int pc = pos_ctx[b];
  int ni[Kn];
#pragma unroll
  for (int k = 0; k < Kn; ++k) ni[k] = neg_ctx[b * Kn + k];

  // Issue all 18 row gathers back-to-back.
  // word row: 512 B fp32 (float2/lane). con rows: 128 B fp8 (ushort/lane).
  const float2 wv = W[(size_t)cw * 64 + lane];
  const unsigned short cvb = con8[(size_t)pc * 64 + lane];
  unsigned short nvb[Kn];
#pragma unroll
  for (int k = 0; k < Kn; ++k) nvb[k] = con8[(size_t)ni[k] * 64 + lane];

  float v[Kn];
#pragma unroll
  for (int k = 0; k < Kn; ++k) {
    const f32x2 nf = dec2_fp8(nvb[k]);     // 1 hw cvt per row
    v[k] = fmaf(wv.x, nf.x, wv.y * nf.y);
  }

  // 16 partial dots -> one score per lane (15 shuffles), then close the
  // sum across the four 16-lane subgroups (2 shuffles).
  tree_step<1, 16>(v, lane);
  tree_step<2,  8>(v, lane);
  tree_step<4,  4>(v, lane);
  tree_step<8,  2>(v, lane);
  float s = v[0];
  s += __shfl_xor(s, 16, 64);
  s += __shfl_xor(s, 32, 64);
  s *= INV_SCALE;                          // undo e4m3 pre-scale

  float nls = log_sigmoid_fast(-s);        // one SIMD eval = all 16 scores
  nls += __shfl_xor(nls, 1, 64);
  nls += __shfl_xor(nls, 2, 64);
  nls += __shfl_xor(nls, 4, 64);
  nls += __shfl_xor(nls, 8, 64);           // neg_loss total (all lanes)

  const f32x2 cf = dec2_fp8(cvb);
  float pp = fmaf(wv.x, cf.x, wv.y * cf.y);
  pp += __shfl_xor(pp,  1, 64);
  pp += __shfl_xor(pp,  2, 64);
  pp += __shfl_xor(pp,  4, 64);
  pp += __shfl_xor(pp,  8, 64);
  pp += __shfl_xor(pp, 16, 64);
  pp += __shfl_xor(pp, 32, 64);
  pp *= INV_SCALE;                         // undo e4m3 pre-scale

  const float acc = log_sigmoid_fast(pp) + nls;

  __shared__ float smem[WPB];
  if (lane == 0) smem[threadIdx.x >> 6] = acc;
  __syncthreads();
  if (threadIdx.x == 0)
    block_sums[blockIdx.x] = (smem[0] + smem[1]) + (smem[2] + smem[3]);
}

__global__ __launch_bounds__(256) void skipgram_reduce(
    const float* __restrict__ block_sums, float* __restrict__ out)
{
  float s = 0.0f;
#pragma unroll
  for (int i = 0; i < NBLK / 256; ++i) s += block_sums[i * 256 + threadIdx.x];
  s += __shfl_xor(s,  1, 64);
  s += __shfl_xor(s,  2, 64);
  s += __shfl_xor(s,  4, 64);
  s += __shfl_xor(s,  8, 64);
  s += __shfl_xor(s, 16, 64);
  s += __shfl_xor(s, 32, 64);
  __shared__ float smem[4];
  const int lane = threadIdx.x & 63;
  if (lane == 0) smem[threadIdx.x >> 6] = s;
  __syncthreads();
  if (threadIdx.x == 0) {
    float t = (smem[0] + smem[1]) + (smem[2] + smem[3]);
    out[0] = -t * (1.0f / (float)Bn);     // loss = -mean(pos_loss + neg_loss)
  }
}

extern "C" void kernel_launch(void* const* d_in, const int* in_sizes, int n_in,
                              void* d_out, int out_size, void* d_ws, size_t ws_size,
                              hipStream_t stream) {
  const int*   centrals = (const int*)d_in[0];
  const int*   pos_ctx  = (const int*)d_in[1];
  const int*   neg_ctx  = (const int*)d_in[2];
  const float* word_emb = (const float*)d_in[3];
  const float* con_emb  = (const float*)d_in[4];
  float*       out      = (float*)d_out;

  float*        block_sums = (float*)d_ws;                     // 32 KB
  unsigned int* con_fp8 = (unsigned int*)((char*)d_ws + CONV_OFF); // 12.8 MB

  // 1) fp32 -> e4m3 conversion (streaming, 64 MB traffic, hw cvt).
  const int n4 = VOCAB * DIM / 4;                              // 3.2M float4
  convert_con<<<(n4 + 255) / 256, 256, 0, stream>>>(
      (const float4*)con_emb, con_fp8, n4);

  // 2) gathers + dots + log-sigmoid -> per-block partials.
  skipgram_main<<<NBLK, 256, 0, stream>>>(centrals, pos_ctx, neg_ctx,
                                          word_emb,
                                          (const unsigned short*)con_fp8,
                                          block_sums);

  // 3) final mean.
  skipgram_reduce<<<1, 256, 0, stream>>>(block_sums, out);
}